// Round 12
// baseline (1688.683 us; speedup 1.0000x reference)
//
#include <hip/hip_runtime.h>
#include <math.h>

#define KB       4            // logical ranks (blocks doing work)
#define NBOOT    32           // launched blocks; ranks = {0,8,16,24} (bid%8==0 -> XCD0)
#define NTHREADS 256
#define NW       4            // waves per block
#define HID      4096
#define HB       (HID / KB)   // 1024 neurons per rank
#define NPT      4            // neurons per thread
#define TT       1000
#define PP       16
#define SLOTW    32           // u64 stride per rank-slot (256B, line-aligned)

#define BETA 0.9f
#define THRV 0.5f
#define DTV  0.005f

// DPP cross-lane: quad_perm {1,0,3,2}=0xB1 (lane^1), {2,3,0,1}=0x4E (lane^2),
// row_ror:8 = 0x128 (lane^8 within row-of-16). All VALU-pipe (no DS).
template<int CTRL>
__device__ __forceinline__ float dppx(float v) {
    return __int_as_float(__builtin_amdgcn_update_dpp(
        0, __float_as_int(v), CTRL, 0xF, 0xF, true));
}

__device__ __forceinline__ unsigned long long AL(const unsigned long long* p) {
    return __hip_atomic_load(p, __ATOMIC_RELAXED, __HIP_MEMORY_SCOPE_AGENT);
}
__device__ __forceinline__ void AS(unsigned long long* p, unsigned long long v) {
    __hip_atomic_store(p, v, __ATOMIC_RELAXED, __HIP_MEMORY_SCOPE_AGENT);
}
// writer fast path: plain store -> write-through vL1 -> lands in writer's XCD L2
__device__ __forceinline__ void st64_plain(unsigned long long* p, unsigned long long v) {
    asm volatile("global_store_dwordx2 %0, %1, off" :: "v"(p), "v"(v) : "memory");
}
// reader fast path: invalidate own vL1 (compiler's acquire primitive), then plain
// loads -> L1 miss -> same-XCD L2 hit with the writer's fresh line (~200 cyc).
__device__ __forceinline__ void inv_ld3(const unsigned long long* p0,
                                        const unsigned long long* p1,
                                        const unsigned long long* p2,
                                        unsigned long long& v0,
                                        unsigned long long& v1,
                                        unsigned long long& v2) {
    asm volatile("buffer_inv sc0\n\t"
                 "global_load_dwordx2 %0, %3, off\n\t"
                 "global_load_dwordx2 %1, %4, off\n\t"
                 "global_load_dwordx2 %2, %5, off\n\t"
                 "s_waitcnt vmcnt(0)"
                 : "=&v"(v0), "=&v"(v1), "=&v"(v2)
                 : "v"(p0), "v"(p1), "v"(p2) : "memory");
}

__global__ __launch_bounds__(NTHREADS, 1)
void snn_kernel(const float* __restrict__ x,
                const float* __restrict__ noise,
                const float* __restrict__ Win,
                const float* __restrict__ Wout,
                const float* __restrict__ pin,
                const float* __restrict__ pout,
                const float* __restrict__ lvec,
                const float* __restrict__ stdv,
                float* __restrict__ ypart,
                unsigned long long* __restrict__ slotsL2,
                unsigned long long* __restrict__ slotsAG)
{
    const int bid  = blockIdx.x;
    if ((bid & 7) != 0) return;          // ranks live on XCD (bid%8)==0 only
    const int b    = bid >> 3;           // logical rank 0..3 (blocks 0,8,16,24)
    const int tid  = threadIdx.x;
    const int wave = tid >> 6;
    const int lane = tid & 63;
    const int h0   = b * HB + tid * NPT; // four consecutive neurons per thread

    const bool lb0 = (lane & 1) != 0;
    const bool lb1 = (lane & 2) != 0;
    const bool lb2 = (lane & 4) != 0;
    const bool lb3 = (lane & 8) != 0;

    // remote rank indices in ascending order (for canonical sum tree)
    const int rbA = (b == 0) ? 1 : 0;
    const int rbB = (b <= 1) ? 2 : 1;
    const int rbC = (b <= 2) ? 3 : 2;

    __shared__ float part[NW][20];       // per-wave butterfly results (u:0-15, y:16-17)
    __shared__ float ubuf[NW][16];       // per-wave u broadcast area

    // ---------------- parameter load (once) ----------------
    float lv[PP];
    #pragma unroll
    for (int p = 0; p < PP; p += 4) {
        float4 t4 = *(const float4*)&lvec[p];
        lv[p] = t4.x; lv[p+1] = t4.y; lv[p+2] = t4.z; lv[p+3] = t4.w;
    }
    float pl[NPT][PP], po[NPT][PP];
    #pragma unroll
    for (int j = 0; j < NPT; ++j) {
        #pragma unroll
        for (int p = 0; p < PP; p += 4) {
            float4 a = *(const float4*)&pin[(h0+j)*PP + p];
            pl[j][p]   = a.x*lv[p];   pl[j][p+1] = a.y*lv[p+1];
            pl[j][p+2] = a.z*lv[p+2]; pl[j][p+3] = a.w*lv[p+3];
            float4 e4 = *(const float4*)&pout[(h0+j)*PP + p];
            po[j][p]   = e4.x; po[j][p+1] = e4.y;
            po[j][p+2] = e4.z; po[j][p+3] = e4.w;
        }
    }
    float win[NPT][6];
    #pragma unroll
    for (int j = 0; j < NPT; ++j) {
        const float2* wr = (const float2*)&Win[(h0+j)*6];
        float2 wA = wr[0], wB = wr[1], wC = wr[2];
        win[j][0]=wA.x; win[j][1]=wA.y; win[j][2]=wB.x;
        win[j][3]=wB.y; win[j][4]=wC.x; win[j][5]=wC.y;
    }
    float4 woa = *(const float4*)&Wout[h0];        // Wout[0][h0..h0+3]
    float4 wob = *(const float4*)&Wout[HID + h0];  // Wout[1][h0..h0+3]

    float4 sd4 = *(const float4*)&stdv[h0];
    float dd[NPT], sg[NPT];
    {
        float sdv[4] = { sd4.x, sd4.y, sd4.z, sd4.w };
        #pragma unroll
        for (int j = 0; j < NPT; ++j) {
            float sig = 1.f / (1.f + expf(-sdv[j]));
            float tau = sig * 0.03f + 0.02f;
            dd[j] = expf(-DTV / tau);
            sg[j] = DTV / (tau * 0.002f);
        }
    }
    const float DECAY_R = expf(-2.5f);
    const float DTE     = DTV * DECAY_R;

    // ---------------- state ----------------
    float mem[NPT], rr[NPT], ss[NPT];
    float pre[NPT], rlin[NPT], slin[NPT];
    float palin[PP], yalin = 0.f, yblin = 0.f;
    #pragma unroll
    for (int j = 0; j < NPT; ++j) { mem[j]=0.f; rr[j]=0.f; ss[j]=0.f; }
    #pragma unroll
    for (int p = 0; p < PP; ++p) palin[p] = 0.f;

    const float2* x2 = (const float2*)x;
    float4 nz = *(const float4*)&noise[h0];           // t = 0
    float2 xa = x2[0], xb = x2[1], xc = x2[2];

    float uu[16];
    #pragma unroll
    for (int p = 0; p < 16; ++p) uu[p] = 0.f;

    int use_l2 = 1;    // sticky per-wave: drop to agent polling if L2 path dead

    for (int t = 0; t <= TT; ++t) {
        const int par = t & 1;

        // ---- top of step: block sum of deposited parts; publish tag t ----
        float bs = 0.f;
        if (t > 0) {
            if (lane < 18) {
                bs = (part[0][lane] + part[1][lane])
                   + (part[2][lane] + part[3][lane]);
            }
            if (wave == 0) {
                if (lane < 16) {
                    if (t < TT) {      // nobody polls t==TT
                        union { float f; unsigned u; } cv; cv.f = bs;
                        unsigned long long pk =
                            ((unsigned long long)(unsigned)t << 32)
                          | (unsigned long long)cv.u;
                        const size_t si = (size_t)(par*KB + b)*SLOTW + lane;
                        st64_plain(&slotsL2[si], pk);   // fast: shared-XCD L2
                        AS(&slotsAG[si], pk);           // hedge: far coherence point
                    }
                } else if (lane < 18) {
                    // block-private y partial of y[t-1] (plain store)
                    ypart[(size_t)b*(2*TT) + (t-1)*2 + (lane-16)] = bs;
                }
            }
        }

        // ---- visibility window: u-independent work for step t ----
        if (t < TT) {
            float nzv[4] = { nz.x, nz.y, nz.z, nz.w };
            #pragma unroll
            for (int j = 0; j < NPT; ++j) {
                float xw = win[j][0]*xa.x + win[j][1]*xa.y
                         + win[j][2]*xb.x + win[j][3]*xb.y
                         + win[j][4]*xc.x + win[j][5]*xc.y;
                float rst = (mem[j] - THRV > 0.f) ? THRV : 0.f;
                pre[j]  = BETA*mem[j] + xw + nzv[j] / 10.0f - rst;
                rlin[j] = dd[j]*rr[j] + DTE*ss[j];
                slin[j] = DECAY_R*ss[j];
            }
            #pragma unroll
            for (int p = 0; p < PP; ++p)
                palin[p] = (po[0][p]*rlin[0] + po[1][p]*rlin[1])
                         + (po[2][p]*rlin[2] + po[3][p]*rlin[3]);
            yalin = (woa.x*rlin[0]+woa.y*rlin[1]) + (woa.z*rlin[2]+woa.w*rlin[3]);
            yblin = (wob.x*rlin[0]+wob.y*rlin[1]) + (wob.z*rlin[2]+wob.w*rlin[3]);
        }

        // ---- poll 3 remote ranks' tagged lines: L2 fast path, agent fallback ----
        if (t > 0 && t < TT) {
            const size_t sb = (size_t)par * KB;
            float f0 = 0.f, f1 = 0.f, f2 = 0.f;
            unsigned long long va = 0, vb = 0, vc = 0;
            int got = (lane < 16) ? 0 : 1;
            if (use_l2) {
                if (lane < 16) {
                    const unsigned long long* pa_ = &slotsL2[(sb + rbA)*SLOTW + lane];
                    const unsigned long long* pb_ = &slotsL2[(sb + rbB)*SLOTW + lane];
                    const unsigned long long* pc_ = &slotsL2[(sb + rbC)*SLOTW + lane];
                    const int K = (t == 1) ? 1024 : 64;
                    int sp = 0, ok;
                    do {
                        inv_ld3(pa_, pb_, pc_, va, vb, vc);
                        ok = ((unsigned)(va >> 32) == (unsigned)t)
                           & ((unsigned)(vb >> 32) == (unsigned)t)
                           & ((unsigned)(vc >> 32) == (unsigned)t);
                    } while (!ok && ++sp < K);
                    got = ok;
                }
                if (!__all(got)) use_l2 = 0;   // wave-uniform sticky fallback
            }
            if (!use_l2) {
                if (lane < 16 && !got) {
                    const unsigned long long* pa_ = &slotsAG[(sb + rbA)*SLOTW + lane];
                    const unsigned long long* pb_ = &slotsAG[(sb + rbB)*SLOTW + lane];
                    const unsigned long long* pc_ = &slotsAG[(sb + rbC)*SLOTW + lane];
                    int sp2 = 0;
                    do {
                        va = AL(pa_); vb = AL(pb_); vc = AL(pc_);
                    } while ((((unsigned)(va >> 32) != (unsigned)t) |
                              ((unsigned)(vb >> 32) != (unsigned)t) |
                              ((unsigned)(vc >> 32) != (unsigned)t)) &&
                             ++sp2 < (1 << 20));
                }
            }
            if (lane < 16) {
                union { unsigned u; float f; } c0, c1, c2;
                c0.u = (unsigned)va; c1.u = (unsigned)vb; c2.u = (unsigned)vc;
                f0 = c0.f; f1 = c1.f; f2 = c2.f;
            }
            // canonical rank-order tree: (R0+R1)+(R2+R3), identical everywhere
            float total = (b < 2) ? ((bs + f0) + (f1 + f2))
                                  : ((f0 + f1) + (f2 + bs));
            if (lane < 16) ubuf[wave][lane] = total;
            float4 u0 = *(const float4*)&ubuf[wave][0];
            float4 u1 = *(const float4*)&ubuf[wave][4];
            float4 u2 = *(const float4*)&ubuf[wave][8];
            float4 u3 = *(const float4*)&ubuf[wave][12];
            uu[0]=u0.x; uu[1]=u0.y; uu[2]=u0.z; uu[3]=u0.w;
            uu[4]=u1.x; uu[5]=u1.y; uu[6]=u1.z; uu[7]=u1.w;
            uu[8]=u2.x; uu[9]=u2.y; uu[10]=u2.z; uu[11]=u2.w;
            uu[12]=u3.x; uu[13]=u3.y; uu[14]=u3.z; uu[15]=u3.w;
        }

        // ---- update + next projection + butterfly + deposit ----
        if (t < TT) {
            // prefetch next step's inputs (overlaps update + next publish)
            if (t < TT - 1) {
                const int tn = t + 1;
                nz = *(const float4*)&noise[tn * HID + h0];
                xa = x2[tn*3]; xb = x2[tn*3+1]; xc = x2[tn*3+2];
            }

            float rs[NPT];
            #pragma unroll
            for (int j = 0; j < NPT; ++j) {
                float ra  = pl[j][0]*uu[0];
                float rb_ = pl[j][8]*uu[8];
                #pragma unroll
                for (int p = 1; p < 8; ++p) {
                    ra  += pl[j][p]*uu[p];
                    rb_ += pl[j][p+8]*uu[p+8];
                }
                mem[j] = pre[j] + (ra + rb_);
                bool spk = (mem[j] - THRV > 0.f);
                float rspk = spk ? DTV*sg[j] : 0.f;
                ss[j] = slin[j] + (spk ? sg[j] : 0.f);
                rr[j] = rlin[j] + rspk;
                rs[j] = rspk;
            }
            float pa[18];
            #pragma unroll
            for (int p = 0; p < PP; ++p)
                pa[p] = palin[p] + ((po[0][p]*rs[0] + po[1][p]*rs[1])
                                 +  (po[2][p]*rs[2] + po[3][p]*rs[3]));
            pa[16] = yalin + ((woa.x*rs[0]+woa.y*rs[1]) + (woa.z*rs[2]+woa.w*rs[3]));
            pa[17] = yblin + ((wob.x*rs[0]+wob.y*rs[1]) + (wob.z*rs[2]+wob.w*rs[3]));

            // reduce-scatter butterfly: lane ends with u[lane&15] / y[lane&1]
            float a1[8], yv;
            #pragma unroll
            for (int k = 0; k < 8; ++k) {
                float keep = lb0 ? pa[2*k+1] : pa[2*k];
                float send = lb0 ? pa[2*k]   : pa[2*k+1];
                a1[k] = keep + dppx<0xB1>(send);          // xor1 (DPP)
            }
            {
                float keep = lb0 ? pa[17] : pa[16];
                float send = lb0 ? pa[16] : pa[17];
                yv = keep + dppx<0xB1>(send);
            }
            float a2[4];
            #pragma unroll
            for (int k = 0; k < 4; ++k) {
                float keep = lb1 ? a1[2*k+1] : a1[2*k];
                float send = lb1 ? a1[2*k]   : a1[2*k+1];
                a2[k] = keep + dppx<0x4E>(send);          // xor2 (DPP)
            }
            yv += dppx<0x4E>(yv);
            float a3[2];
            #pragma unroll
            for (int k = 0; k < 2; ++k) {
                float keep = lb2 ? a2[2*k+1] : a2[2*k];
                float send = lb2 ? a2[2*k]   : a2[2*k+1];
                a3[k] = keep + __shfl_xor(send, 4, 64);   // xor4 (DS)
            }
            yv += __shfl_xor(yv, 4, 64);
            float uv;
            {
                float keep = lb3 ? a3[1] : a3[0];
                float send = lb3 ? a3[0] : a3[1];
                uv = keep + dppx<0x128>(send);            // xor8 (DPP row_ror:8)
            }
            yv += dppx<0x128>(yv);
            uv += __shfl_xor(uv, 16, 64);                 // xor16 (DS)
            uv += __shfl_xor(uv, 32, 64);                 // xor32 (DS)
            yv += __shfl_xor(yv, 16, 64);
            yv += __shfl_xor(yv, 32, 64);

            if (lane < 18) part[wave][lane] = (lane < 16) ? uv : yv;
            __syncthreads();   // deposit->read separation; poll next iter >> read time
        }
    }
}

__global__ void ysum_kernel(const float* __restrict__ yp, float* __restrict__ out) {
    int i = blockIdx.x * blockDim.x + threadIdx.x;
    if (i < 2 * TT) {
        float a = yp[i];
        float b = yp[2*TT + i];
        float c = yp[2*2*TT + i];
        float d = yp[3*2*TT + i];
        out[i] = (a + b) + (c + d);    // canonical (R0+R1)+(R2+R3)
    }
}

extern "C" void kernel_launch(void* const* d_in, const int* in_sizes, int n_in,
                              void* d_out, int out_size, void* d_ws, size_t ws_size,
                              hipStream_t stream)
{
    const float* x     = (const float*)d_in[0];
    const float* noise = (const float*)d_in[1];
    const float* Win   = (const float*)d_in[2];
    const float* Wout  = (const float*)d_in[3];
    const float* pin   = (const float*)d_in[4];
    const float* pout  = (const float*)d_in[5];
    const float* l     = (const float*)d_in[6];
    const float* stdv  = (const float*)d_in[7];
    float* out = (float*)d_out;
    unsigned long long* slotsL2 = (unsigned long long*)d_ws;                  // 2KB
    unsigned long long* slotsAG = (unsigned long long*)((char*)d_ws + 4096);  // 2KB
    float* ypart = (float*)((char*)d_ws + 8192);                              // 32KB

    hipLaunchKernelGGL(snn_kernel, dim3(NBOOT), dim3(NTHREADS), 0, stream,
                       x, noise, Win, Wout, pin, pout, l, stdv,
                       ypart, slotsL2, slotsAG);
    hipLaunchKernelGGL(ysum_kernel, dim3((2*TT + 255)/256), dim3(256), 0, stream,
                       ypart, out);
}

// Round 13
// 1613.324 us; speedup vs baseline: 1.0467x; 1.0467x over previous
//
#include <hip/hip_runtime.h>
#include <math.h>

#define KB       4            // blocks (one per CU)
#define NTHREADS 256
#define NW       4            // waves per block
#define HID      4096
#define HB       (HID / KB)   // 1024 neurons per block
#define NPT      4            // neurons per thread
#define TT       1000
#define PP       16
#define SLOTW    32           // u64 stride per block-slot (256B, line-aligned)

#define BETA 0.9f
#define THRV 0.5f
#define DTV  0.005f

// DPP cross-lane: quad_perm {1,0,3,2}=0xB1 (lane^1), {2,3,0,1}=0x4E (lane^2),
// row_ror:8 = 0x128 (lane^8 within row-of-16). All VALU-pipe (no DS).
template<int CTRL>
__device__ __forceinline__ float dppx(float v) {
    return __int_as_float(__builtin_amdgcn_update_dpp(
        0, __float_as_int(v), CTRL, 0xF, 0xF, true));
}

__device__ __forceinline__ unsigned long long AL(const unsigned long long* p) {
    return __hip_atomic_load(p, __ATOMIC_RELAXED, __HIP_MEMORY_SCOPE_AGENT);
}
__device__ __forceinline__ void AS(unsigned long long* p, unsigned long long v) {
    __hip_atomic_store(p, v, __ATOMIC_RELAXED, __HIP_MEMORY_SCOPE_AGENT);
}

__global__ __launch_bounds__(NTHREADS, 1)
void snn_kernel(const float* __restrict__ x,
                const float* __restrict__ noise,
                const float* __restrict__ Win,
                const float* __restrict__ Wout,
                const float* __restrict__ pin,
                const float* __restrict__ pout,
                const float* __restrict__ lvec,
                const float* __restrict__ stdv,
                float* __restrict__ ypart,
                unsigned long long* __restrict__ slots)
{
    const int b    = blockIdx.x;
    const int tid  = threadIdx.x;
    const int wave = tid >> 6;
    const int lane = tid & 63;
    const int h0   = b * HB + tid * NPT;   // four consecutive neurons per thread

    const bool lb0 = (lane & 1) != 0;
    const bool lb1 = (lane & 2) != 0;
    const bool lb2 = (lane & 4) != 0;
    const bool lb3 = (lane & 8) != 0;

    // remote block indices in ascending order (for canonical sum tree)
    const int rbA = (b == 0) ? 1 : 0;
    const int rbB = (b <= 1) ? 2 : 1;
    const int rbC = (b <= 2) ? 3 : 2;

    __shared__ float part[NW][20];       // per-wave butterfly results (u:0-15, y:16-17)
    __shared__ float ubuf[NW][16];       // per-wave u broadcast area

    // ---------------- parameter load (once) ----------------
    float lv[PP];
    #pragma unroll
    for (int p = 0; p < PP; p += 4) {
        float4 t4 = *(const float4*)&lvec[p];
        lv[p] = t4.x; lv[p+1] = t4.y; lv[p+2] = t4.z; lv[p+3] = t4.w;
    }
    float pl[NPT][PP], po[NPT][PP];
    #pragma unroll
    for (int j = 0; j < NPT; ++j) {
        #pragma unroll
        for (int p = 0; p < PP; p += 4) {
            float4 a = *(const float4*)&pin[(h0+j)*PP + p];
            pl[j][p]   = a.x*lv[p];   pl[j][p+1] = a.y*lv[p+1];
            pl[j][p+2] = a.z*lv[p+2]; pl[j][p+3] = a.w*lv[p+3];
            float4 e4 = *(const float4*)&pout[(h0+j)*PP + p];
            po[j][p]   = e4.x; po[j][p+1] = e4.y;
            po[j][p+2] = e4.z; po[j][p+3] = e4.w;
        }
    }
    float win[NPT][6];
    #pragma unroll
    for (int j = 0; j < NPT; ++j) {
        const float2* wr = (const float2*)&Win[(h0+j)*6];
        float2 wA = wr[0], wB = wr[1], wC = wr[2];
        win[j][0]=wA.x; win[j][1]=wA.y; win[j][2]=wB.x;
        win[j][3]=wB.y; win[j][4]=wC.x; win[j][5]=wC.y;
    }
    float4 woa = *(const float4*)&Wout[h0];        // Wout[0][h0..h0+3]
    float4 wob = *(const float4*)&Wout[HID + h0];  // Wout[1][h0..h0+3]

    float4 sd4 = *(const float4*)&stdv[h0];
    float dd[NPT], sg[NPT];
    {
        float sdv[4] = { sd4.x, sd4.y, sd4.z, sd4.w };
        #pragma unroll
        for (int j = 0; j < NPT; ++j) {
            float sig = 1.f / (1.f + expf(-sdv[j]));
            float tau = sig * 0.03f + 0.02f;
            dd[j] = expf(-DTV / tau);
            sg[j] = DTV / (tau * 0.002f);
        }
    }
    const float DECAY_R = expf(-2.5f);
    const float DTE     = DTV * DECAY_R;

    // ---------------- state ----------------
    float mem[NPT], rr[NPT], ss[NPT];
    float pre[NPT], rlin[NPT], slin[NPT];
    float palin[PP], yalin = 0.f, yblin = 0.f;
    #pragma unroll
    for (int j = 0; j < NPT; ++j) { mem[j]=0.f; rr[j]=0.f; ss[j]=0.f; }
    #pragma unroll
    for (int p = 0; p < PP; ++p) palin[p] = 0.f;

    const float2* x2 = (const float2*)x;
    float4 nz = *(const float4*)&noise[h0];           // t = 0
    float2 xa = x2[0], xb = x2[1], xc = x2[2];

    float uu[16];
    #pragma unroll
    for (int p = 0; p < 16; ++p) uu[p] = 0.f;

    for (int t = 0; t <= TT; ++t) {
        const int par = t & 1;

        // ---- top of step: block sum of deposited parts; publish tag t ----
        float bs = 0.f;
        if (t > 0) {
            if (lane < 18) {
                bs = (part[0][lane] + part[1][lane])
                   + (part[2][lane] + part[3][lane]);
            }
            if (wave == 0) {
                if (lane < 16) {
                    if (t < TT) {      // nobody polls t==TT
                        union { float f; unsigned u; } cv; cv.f = bs;
                        unsigned long long pk =
                            ((unsigned long long)(unsigned)t << 32)
                          | (unsigned long long)cv.u;
                        AS(&slots[(size_t)(par*KB + b)*SLOTW + lane], pk);
                    }
                } else if (lane < 18) {
                    // block-private y partial of y[t-1] (plain store)
                    ypart[(size_t)b*(2*TT) + (t-1)*2 + (lane-16)] = bs;
                }
            }
        }

        // ---- visibility window: u-independent work for step t ----
        if (t < TT) {
            float nzv[4] = { nz.x, nz.y, nz.z, nz.w };
            #pragma unroll
            for (int j = 0; j < NPT; ++j) {
                float xw = win[j][0]*xa.x + win[j][1]*xa.y
                         + win[j][2]*xb.x + win[j][3]*xb.y
                         + win[j][4]*xc.x + win[j][5]*xc.y;
                float rst = (mem[j] - THRV > 0.f) ? THRV : 0.f;
                pre[j]  = BETA*mem[j] + xw + nzv[j] / 10.0f - rst;
                rlin[j] = dd[j]*rr[j] + DTE*ss[j];
                slin[j] = DECAY_R*ss[j];
            }
            #pragma unroll
            for (int p = 0; p < PP; ++p)
                palin[p] = (po[0][p]*rlin[0] + po[1][p]*rlin[1])
                         + (po[2][p]*rlin[2] + po[3][p]*rlin[3]);
            yalin = (woa.x*rlin[0]+woa.y*rlin[1]) + (woa.z*rlin[2]+woa.w*rlin[3]);
            yblin = (wob.x*rlin[0]+wob.y*rlin[1]) + (wob.z*rlin[2]+wob.w*rlin[3]);
        }

        // ---- poll 3 remote blocks' tagged lines (agent scope, proven path) ----
        if (t > 0 && t < TT) {
            const size_t sb = (size_t)par * KB;
            float f0 = 0.f, f1 = 0.f, f2 = 0.f;
            if (lane < 16) {
                const unsigned long long* pa_ = &slots[(sb + rbA)*SLOTW + lane];
                const unsigned long long* pb_ = &slots[(sb + rbB)*SLOTW + lane];
                const unsigned long long* pc_ = &slots[(sb + rbC)*SLOTW + lane];
                unsigned long long va, vb, vc;
                int sp = 0;
                do {
                    va = AL(pa_); vb = AL(pb_); vc = AL(pc_);
                } while ((((unsigned)(va >> 32) != (unsigned)t) |
                          ((unsigned)(vb >> 32) != (unsigned)t) |
                          ((unsigned)(vc >> 32) != (unsigned)t)) &&
                         ++sp < (1 << 20));
                union { unsigned u; float f; } c0, c1, c2;
                c0.u = (unsigned)va; c1.u = (unsigned)vb; c2.u = (unsigned)vc;
                f0 = c0.f; f1 = c1.f; f2 = c2.f;
            }
            // canonical block-order tree: (B0+B1)+(B2+B3), identical everywhere
            float total = (b < 2) ? ((bs + f0) + (f1 + f2))
                                  : ((f0 + f1) + (f2 + bs));
            if (lane < 16) ubuf[wave][lane] = total;
            float4 u0 = *(const float4*)&ubuf[wave][0];
            float4 u1 = *(const float4*)&ubuf[wave][4];
            float4 u2 = *(const float4*)&ubuf[wave][8];
            float4 u3 = *(const float4*)&ubuf[wave][12];
            uu[0]=u0.x; uu[1]=u0.y; uu[2]=u0.z; uu[3]=u0.w;
            uu[4]=u1.x; uu[5]=u1.y; uu[6]=u1.z; uu[7]=u1.w;
            uu[8]=u2.x; uu[9]=u2.y; uu[10]=u2.z; uu[11]=u2.w;
            uu[12]=u3.x; uu[13]=u3.y; uu[14]=u3.z; uu[15]=u3.w;
        }

        // ---- update + next projection + butterfly + deposit ----
        if (t < TT) {
            // prefetch next step's inputs (overlaps update + next publish)
            if (t < TT - 1) {
                const int tn = t + 1;
                nz = *(const float4*)&noise[tn * HID + h0];
                xa = x2[tn*3]; xb = x2[tn*3+1]; xc = x2[tn*3+2];
            }

            float rs[NPT];
            #pragma unroll
            for (int j = 0; j < NPT; ++j) {
                float ra  = pl[j][0]*uu[0];
                float rb_ = pl[j][8]*uu[8];
                #pragma unroll
                for (int p = 1; p < 8; ++p) {
                    ra  += pl[j][p]*uu[p];
                    rb_ += pl[j][p+8]*uu[p+8];
                }
                mem[j] = pre[j] + (ra + rb_);
                bool spk = (mem[j] - THRV > 0.f);
                float rspk = spk ? DTV*sg[j] : 0.f;
                ss[j] = slin[j] + (spk ? sg[j] : 0.f);
                rr[j] = rlin[j] + rspk;
                rs[j] = rspk;
            }
            float pa[18];
            #pragma unroll
            for (int p = 0; p < PP; ++p)
                pa[p] = palin[p] + ((po[0][p]*rs[0] + po[1][p]*rs[1])
                                 +  (po[2][p]*rs[2] + po[3][p]*rs[3]));
            pa[16] = yalin + ((woa.x*rs[0]+woa.y*rs[1]) + (woa.z*rs[2]+woa.w*rs[3]));
            pa[17] = yblin + ((wob.x*rs[0]+wob.y*rs[1]) + (wob.z*rs[2]+wob.w*rs[3]));

            // reduce-scatter butterfly: lane ends with u[lane&15] / y[lane&1]
            float a1[8], yv;
            #pragma unroll
            for (int k = 0; k < 8; ++k) {
                float keep = lb0 ? pa[2*k+1] : pa[2*k];
                float send = lb0 ? pa[2*k]   : pa[2*k+1];
                a1[k] = keep + dppx<0xB1>(send);          // xor1 (DPP)
            }
            {
                float keep = lb0 ? pa[17] : pa[16];
                float send = lb0 ? pa[16] : pa[17];
                yv = keep + dppx<0xB1>(send);
            }
            float a2[4];
            #pragma unroll
            for (int k = 0; k < 4; ++k) {
                float keep = lb1 ? a1[2*k+1] : a1[2*k];
                float send = lb1 ? a1[2*k]   : a1[2*k+1];
                a2[k] = keep + dppx<0x4E>(send);          // xor2 (DPP)
            }
            yv += dppx<0x4E>(yv);
            float a3[2];
            #pragma unroll
            for (int k = 0; k < 2; ++k) {
                float keep = lb2 ? a2[2*k+1] : a2[2*k];
                float send = lb2 ? a2[2*k]   : a2[2*k+1];
                a3[k] = keep + __shfl_xor(send, 4, 64);   // xor4 (DS)
            }
            yv += __shfl_xor(yv, 4, 64);
            float uv;
            {
                float keep = lb3 ? a3[1] : a3[0];
                float send = lb3 ? a3[0] : a3[1];
                uv = keep + dppx<0x128>(send);            // xor8 (DPP row_ror:8)
            }
            yv += dppx<0x128>(yv);
            uv += __shfl_xor(uv, 16, 64);                 // xor16 (DS)
            uv += __shfl_xor(uv, 32, 64);                 // xor32 (DS)
            yv += __shfl_xor(yv, 16, 64);
            yv += __shfl_xor(yv, 32, 64);

            if (lane < 18) part[wave][lane] = (lane < 16) ? uv : yv;
            __syncthreads();   // deposit->read separation; poll next iter >> read time
        }
    }
}

__global__ void ysum_kernel(const float* __restrict__ yp, float* __restrict__ out) {
    int i = blockIdx.x * blockDim.x + threadIdx.x;
    if (i < 2 * TT) {
        float a = yp[i];
        float b = yp[2*TT + i];
        float c = yp[2*2*TT + i];
        float d = yp[3*2*TT + i];
        out[i] = (a + b) + (c + d);    // canonical (B0+B1)+(B2+B3)
    }
}

extern "C" void kernel_launch(void* const* d_in, const int* in_sizes, int n_in,
                              void* d_out, int out_size, void* d_ws, size_t ws_size,
                              hipStream_t stream)
{
    const float* x     = (const float*)d_in[0];
    const float* noise = (const float*)d_in[1];
    const float* Win   = (const float*)d_in[2];
    const float* Wout  = (const float*)d_in[3];
    const float* pin   = (const float*)d_in[4];
    const float* pout  = (const float*)d_in[5];
    const float* l     = (const float*)d_in[6];
    const float* stdv  = (const float*)d_in[7];
    float* out = (float*)d_out;
    unsigned long long* slots = (unsigned long long*)d_ws;       // 2*4*32*8 = 2 KB
    float* ypart = (float*)((char*)d_ws + 4096);                 // 4 * 2000 floats

    hipLaunchKernelGGL(snn_kernel, dim3(KB), dim3(NTHREADS), 0, stream,
                       x, noise, Win, Wout, pin, pout, l, stdv,
                       ypart, slots);
    hipLaunchKernelGGL(ysum_kernel, dim3((2*TT + 255)/256), dim3(256), 0, stream,
                       ypart, out);
}